// Round 5
// baseline (216.134 us; speedup 1.0000x reference)
//
#include <hip/hip_runtime.h>

// Problem constants (fixed by reference setup_inputs)
#define NB 65536   // batch
#define NT 64      // time points -> 63 Euler steps
#define NH 64      // hidden width (ode + classifier)
#define NC 3       // classes

// tanh(x) = 1 - 2/(exp(2x)+1), via hardware exp2 + rcp (2 trans ops, 3 VALU).
// Saturates exactly to +/-1 on overflow/underflow, which matches tanh limits.
__device__ __forceinline__ float fast_tanh(float x) {
#if __has_builtin(__builtin_amdgcn_exp2f)
    float e = __builtin_amdgcn_exp2f(x * 2.8853900817779268f); // 2*log2(e)
#else
    float e = __expf(x * 2.0f);
#endif
#if __has_builtin(__builtin_amdgcn_rcpf)
    float r = __builtin_amdgcn_rcpf(e + 1.0f);
#else
    float r = 1.0f / (e + 1.0f);
#endif
    return fmaf(-2.0f, r, 1.0f);
}

__global__ __launch_bounds__(256, 1) void node_fused(
    const float* __restrict__ y0,
    const float* __restrict__ t,
    const float* __restrict__ W1,  const float* __restrict__ b1,
    const float* __restrict__ W2,  const float* __restrict__ b2,
    const float* __restrict__ Wc1, const float* __restrict__ bc1,
    const float* __restrict__ Wc2, const float* __restrict__ bc2,
    const float* __restrict__ Wc3, const float* __restrict__ bc3,
    float* __restrict__ out)
{
    const int i = blockIdx.x * blockDim.x + threadIdx.x;

    const float2 y = *reinterpret_cast<const float2*>(y0 + 2 * i);
    float yA = y.x, yB = y.y;

    // ----- ODE: 63 forward-Euler steps of f(y) = tanh(y@W1 + b1) @ W2 + b2 -----
    for (int s = 0; s < NT - 1; ++s) {
        const float dt = t[s + 1] - t[s];
        float f0 = b2[0], f1 = b2[1];
        #pragma unroll
        for (int j = 0; j < NH; ++j) {
            // W1 is (2,64) row-major: W1[0][j]=W1[j], W1[1][j]=W1[64+j]
            float pre = fmaf(yA, W1[j], fmaf(yB, W1[NH + j], b1[j]));
            float h = fast_tanh(pre);
            // W2 is (64,2) row-major
            f0 = fmaf(h, W2[2 * j + 0], f0);
            f1 = fmaf(h, W2[2 * j + 1], f1);
        }
        yA = fmaf(dt, f0, yA);
        yB = fmaf(dt, f1, yB);
    }

    // ----- classifier: relu(yT@Wc1+bc1) -> relu(@Wc2+bc2) -> @Wc3+bc3 -----
    float h1[NH];
    #pragma unroll
    for (int j = 0; j < NH; ++j) {
        float pre = fmaf(yA, Wc1[j], fmaf(yB, Wc1[NH + j], bc1[j]));
        h1[j] = fmaxf(pre, 0.0f);
    }

    // h2 = relu(h1 @ Wc2 + bc2); fully unrolled so h1/h2 stay in registers
    float h2[NH];
    #pragma unroll
    for (int j = 0; j < NH; ++j) h2[j] = bc2[j];
    #pragma unroll
    for (int k = 0; k < NH; ++k) {
        const float hk = h1[k];
        #pragma unroll
        for (int j = 0; j < NH; ++j)
            h2[j] = fmaf(hk, Wc2[k * NH + j], h2[j]);
    }

    float o0 = bc3[0], o1 = bc3[1], o2 = bc3[2];
    #pragma unroll
    for (int j = 0; j < NH; ++j) {
        float h = fmaxf(h2[j], 0.0f);
        // Wc3 is (64,3) row-major
        o0 = fmaf(h, Wc3[3 * j + 0], o0);
        o1 = fmaf(h, Wc3[3 * j + 1], o1);
        o2 = fmaf(h, Wc3[3 * j + 2], o2);
    }

    out[3 * i + 0] = o0;
    out[3 * i + 1] = o1;
    out[3 * i + 2] = o2;
}

extern "C" void kernel_launch(void* const* d_in, const int* in_sizes, int n_in,
                              void* d_out, int out_size, void* d_ws, size_t ws_size,
                              hipStream_t stream) {
    (void)in_sizes; (void)n_in; (void)d_ws; (void)ws_size;
    const float* y0  = (const float*)d_in[0];
    const float* t   = (const float*)d_in[1];
    const float* W1  = (const float*)d_in[2];
    const float* b1  = (const float*)d_in[3];
    const float* W2  = (const float*)d_in[4];
    const float* b2  = (const float*)d_in[5];
    const float* Wc1 = (const float*)d_in[6];
    const float* bc1 = (const float*)d_in[7];
    const float* Wc2 = (const float*)d_in[8];
    const float* bc2 = (const float*)d_in[9];
    const float* Wc3 = (const float*)d_in[10];
    const float* bc3 = (const float*)d_in[11];
    float* out = (float*)d_out;

    dim3 block(256);
    dim3 grid(NB / 256);
    hipLaunchKernelGGL(node_fused, grid, block, 0, stream,
                       y0, t, W1, b1, W2, b2, Wc1, bc1, Wc2, bc2, Wc3, bc3, out);
}

// Round 6
// 172.608 us; speedup vs baseline: 1.2522x; 1.2522x over previous
//
#include <hip/hip_runtime.h>

// Problem constants (fixed by reference setup_inputs)
#define NB 65536   // batch
#define NT 64      // time points -> 63 Euler steps
#define NH 64      // hidden width (ode + classifier)
#define NC 3       // classes

typedef float v2 __attribute__((ext_vector_type(2)));

#define TANH_K 2.885390081777927f  // 2*log2(e)

__device__ __forceinline__ float fast_tanh(float x) {
    float e = __builtin_amdgcn_exp2f(x * TANH_K);
    float r = __builtin_amdgcn_rcpf(e + 1.0f);
    return fmaf(-2.0f, r, 1.0f);
}

// lane pair-sum via DPP quad_perm [1,0,3,2] (xor 1) — pure VALU, no LDS
__device__ __forceinline__ float pair_sum(float x) {
#if __has_builtin(__builtin_amdgcn_update_dpp)
    int p = __builtin_amdgcn_update_dpp(0, __float_as_int(x), 0xB1, 0xF, 0xF, true);
    return x + __int_as_float(p);
#else
    return x + __shfl_xor(x, 1, 64);
#endif
}

// ============ Kernel 1: ODE integration, 2 lanes per element ============
// Lane (gid&1) owns hidden units j in [32*(gid&1), 32*(gid&1)+32).
// All weights preloaded to VGPRs; 63-step loop is pure VALU/trans + 2 DPP.
__global__ __launch_bounds__(256, 2) void ode_kernel(
    const float* __restrict__ y0, const float* __restrict__ t,
    const float* __restrict__ W1, const float* __restrict__ b1,
    const float* __restrict__ W2, const float* __restrict__ b2,
    float* __restrict__ yT)
{
    const int gid  = blockIdx.x * blockDim.x + threadIdx.x;
    const int elem = gid >> 1;
    const int half = gid & 1;
    const int jb   = half << 5;           // 0 or 32

    // --- one-time weight preload into registers (per-lane slice) ---
    v2 w1a[16], w1b[16], b1v[16], w2a[16], w2b[16];
    #pragma unroll
    for (int p = 0; p < 16; ++p) {
        const int j = jb + 2 * p;
        w1a[p] = *reinterpret_cast<const v2*>(W1 + j);        // W1[0][j..j+1]
        w1b[p] = *reinterpret_cast<const v2*>(W1 + NH + j);   // W1[1][j..j+1]
        b1v[p] = *reinterpret_cast<const v2*>(b1 + j);
        // W2 is (64,2) row-major: W2[2j+c]
        v2 q0 = *reinterpret_cast<const v2*>(W2 + 2 * j);     // {W2[j][0], W2[j][1]}
        v2 q1 = *reinterpret_cast<const v2*>(W2 + 2 * j + 2); // {W2[j+1][0], W2[j+1][1]}
        v2 a = {q0.x, q1.x}; w2a[p] = a;  // column 0
        v2 b = {q0.y, q1.y}; w2b[p] = b;  // column 1
    }

    v2 yv = *reinterpret_cast<const v2*>(y0 + 2 * elem);
    float yA = yv.x, yB = yv.y;
    const float b20 = b2[0], b21 = b2[1];
    const v2 m2 = {-2.0f, -2.0f};
    const v2 one = {1.0f, 1.0f};

    for (int s = 0; s < NT - 1; ++s) {
        const float dt = t[s + 1] - t[s];
        v2 f0 = {0.0f, 0.0f}, f1 = {0.0f, 0.0f};
        const v2 yAv = {yA, yA}, yBv = {yB, yB};
        #pragma unroll
        for (int p = 0; p < 16; ++p) {
            v2 pre = __builtin_elementwise_fma(yAv, w1a[p],
                     __builtin_elementwise_fma(yBv, w1b[p], b1v[p]));
            v2 tt = pre * TANH_K;
            v2 e = {__builtin_amdgcn_exp2f(tt.x), __builtin_amdgcn_exp2f(tt.y)};
            v2 d = e + 1.0f;
            v2 r = {__builtin_amdgcn_rcpf(d.x), __builtin_amdgcn_rcpf(d.y)};
            v2 h = __builtin_elementwise_fma(m2, r, one);   // tanh
            f0 = __builtin_elementwise_fma(h, w2a[p], f0);
            f1 = __builtin_elementwise_fma(h, w2b[p], f1);
        }
        const float F0 = pair_sum(f0.x + f0.y) + b20;
        const float F1 = pair_sum(f1.x + f1.y) + b21;
        yA = fmaf(dt, F0, yA);
        yB = fmaf(dt, F1, yB);
    }

    // both lanes hold identical yA,yB; each writes one component (coalesced)
    yT[2 * elem + half] = half ? yB : yA;
}

// ============ Kernel 2: classifier, 1 element per lane ============
// Weight access is wave-uniform -> scalar cache; runs once, tiny cost.
__global__ __launch_bounds__(256, 1) void cls_kernel(
    const float* __restrict__ yT,
    const float* __restrict__ Wc1, const float* __restrict__ bc1,
    const float* __restrict__ Wc2, const float* __restrict__ bc2,
    const float* __restrict__ Wc3, const float* __restrict__ bc3,
    float* __restrict__ out)
{
    const int i = blockIdx.x * blockDim.x + threadIdx.x;
    const v2 yv = *reinterpret_cast<const v2*>(yT + 2 * i);
    const float yA = yv.x, yB = yv.y;

    float h1[NH];
    #pragma unroll
    for (int j = 0; j < NH; ++j) {
        float pre = fmaf(yA, Wc1[j], fmaf(yB, Wc1[NH + j], bc1[j]));
        h1[j] = fmaxf(pre, 0.0f);
    }

    float h2[NH];
    #pragma unroll
    for (int j = 0; j < NH; ++j) h2[j] = bc2[j];
    #pragma unroll
    for (int k = 0; k < NH; ++k) {
        const float hk = h1[k];
        #pragma unroll
        for (int j = 0; j < NH; ++j)
            h2[j] = fmaf(hk, Wc2[k * NH + j], h2[j]);
    }

    float o0 = bc3[0], o1 = bc3[1], o2 = bc3[2];
    #pragma unroll
    for (int j = 0; j < NH; ++j) {
        float h = fmaxf(h2[j], 0.0f);
        o0 = fmaf(h, Wc3[3 * j + 0], o0);
        o1 = fmaf(h, Wc3[3 * j + 1], o1);
        o2 = fmaf(h, Wc3[3 * j + 2], o2);
    }

    out[3 * i + 0] = o0;
    out[3 * i + 1] = o1;
    out[3 * i + 2] = o2;
}

// ============ Fallback: round-0 fused kernel (if ws too small) ============
__global__ __launch_bounds__(256, 1) void node_fused(
    const float* __restrict__ y0, const float* __restrict__ t,
    const float* __restrict__ W1,  const float* __restrict__ b1,
    const float* __restrict__ W2,  const float* __restrict__ b2,
    const float* __restrict__ Wc1, const float* __restrict__ bc1,
    const float* __restrict__ Wc2, const float* __restrict__ bc2,
    const float* __restrict__ Wc3, const float* __restrict__ bc3,
    float* __restrict__ out)
{
    const int i = blockIdx.x * blockDim.x + threadIdx.x;
    const float2 y = *reinterpret_cast<const float2*>(y0 + 2 * i);
    float yA = y.x, yB = y.y;
    for (int s = 0; s < NT - 1; ++s) {
        const float dt = t[s + 1] - t[s];
        float f0 = b2[0], f1 = b2[1];
        #pragma unroll
        for (int j = 0; j < NH; ++j) {
            float pre = fmaf(yA, W1[j], fmaf(yB, W1[NH + j], b1[j]));
            float h = fast_tanh(pre);
            f0 = fmaf(h, W2[2 * j + 0], f0);
            f1 = fmaf(h, W2[2 * j + 1], f1);
        }
        yA = fmaf(dt, f0, yA);
        yB = fmaf(dt, f1, yB);
    }
    float h1[NH];
    #pragma unroll
    for (int j = 0; j < NH; ++j)
        h1[j] = fmaxf(fmaf(yA, Wc1[j], fmaf(yB, Wc1[NH + j], bc1[j])), 0.0f);
    float h2[NH];
    #pragma unroll
    for (int j = 0; j < NH; ++j) h2[j] = bc2[j];
    #pragma unroll
    for (int k = 0; k < NH; ++k) {
        const float hk = h1[k];
        #pragma unroll
        for (int j = 0; j < NH; ++j) h2[j] = fmaf(hk, Wc2[k * NH + j], h2[j]);
    }
    float o0 = bc3[0], o1 = bc3[1], o2 = bc3[2];
    #pragma unroll
    for (int j = 0; j < NH; ++j) {
        float h = fmaxf(h2[j], 0.0f);
        o0 = fmaf(h, Wc3[3 * j + 0], o0);
        o1 = fmaf(h, Wc3[3 * j + 1], o1);
        o2 = fmaf(h, Wc3[3 * j + 2], o2);
    }
    out[3 * i + 0] = o0; out[3 * i + 1] = o1; out[3 * i + 2] = o2;
}

extern "C" void kernel_launch(void* const* d_in, const int* in_sizes, int n_in,
                              void* d_out, int out_size, void* d_ws, size_t ws_size,
                              hipStream_t stream) {
    (void)in_sizes; (void)n_in; (void)out_size;
    const float* y0  = (const float*)d_in[0];
    const float* t   = (const float*)d_in[1];
    const float* W1  = (const float*)d_in[2];
    const float* b1  = (const float*)d_in[3];
    const float* W2  = (const float*)d_in[4];
    const float* b2  = (const float*)d_in[5];
    const float* Wc1 = (const float*)d_in[6];
    const float* bc1 = (const float*)d_in[7];
    const float* Wc2 = (const float*)d_in[8];
    const float* bc2 = (const float*)d_in[9];
    const float* Wc3 = (const float*)d_in[10];
    const float* bc3 = (const float*)d_in[11];
    float* out = (float*)d_out;

    const size_t yT_bytes = (size_t)NB * 2 * sizeof(float);
    if (ws_size >= yT_bytes) {
        float* yT = (float*)d_ws;
        // ODE: 2 lanes per element -> 131072 threads
        hipLaunchKernelGGL(ode_kernel, dim3(NB * 2 / 256), dim3(256), 0, stream,
                           y0, t, W1, b1, W2, b2, yT);
        // classifier: 1 element per lane
        hipLaunchKernelGGL(cls_kernel, dim3(NB / 256), dim3(256), 0, stream,
                           yT, Wc1, bc1, Wc2, bc2, Wc3, bc3, out);
    } else {
        hipLaunchKernelGGL(node_fused, dim3(NB / 256), dim3(256), 0, stream,
                           y0, t, W1, b1, W2, b2, Wc1, bc1, Wc2, bc2, Wc3, bc3, out);
    }
}